// Round 20
// baseline (264.930 us; speedup 1.0000x reference)
//
#include <hip/hip_runtime.h>
#include <stdint.h>

typedef __attribute__((ext_vector_type(4))) float f32x4;
typedef __attribute__((ext_vector_type(8))) __bf16 bf16x8;

// ---------- helpers ----------
__device__ __forceinline__ unsigned short f2bf(float f) {
  union { float f; uint32_t u; } v; v.f = f;
  uint32_t u = v.u;
  return (unsigned short)((u + 0x7FFFu + ((u >> 16) & 1u)) >> 16);
}
__device__ __forceinline__ float bflo(uint32_t u) {
  union { uint32_t u; float f; } v; v.u = u << 16; return v.f;
}
__device__ __forceinline__ float bfhi(uint32_t u) {
  union { uint32_t u; float f; } v; v.u = u & 0xffff0000u; return v.f;
}

__device__ __forceinline__ void async_copy16(void* lds, const void* g) {
  __builtin_amdgcn_global_load_lds(
      (const __attribute__((address_space(1))) void*)g,
      (__attribute__((address_space(3))) void*)lds,
      16, 0, 0);
}

// ---------- f32 -> bf16 convert: 3 tensors in one launch ----------
__global__ void cvt3_f32_bf16(const float* __restrict__ in0,
                              const float* __restrict__ in1,
                              const float* __restrict__ in2,
                              uint32_t* __restrict__ out, int n) {
  const float* in = (blockIdx.y == 0) ? in0 : (blockIdx.y == 1) ? in1 : in2;
  uint32_t* o = out + (size_t)blockIdx.y * (n / 2);   // n bf16 = n/2 words
  int i = blockIdx.x * blockDim.x + threadIdx.x;
  int idx = i * 8;
  if (idx >= n) return;
  float4 a = *(const float4*)(in + idx);
  float4 b = *(const float4*)(in + idx + 4);
  uint4 ov;
  ov.x = f2bf(a.x) | ((uint32_t)f2bf(a.y) << 16);
  ov.y = f2bf(a.z) | ((uint32_t)f2bf(a.w) << 16);
  ov.z = f2bf(b.x) | ((uint32_t)f2bf(b.y) << 16);
  ov.w = f2bf(b.z) | ((uint32_t)f2bf(b.w) << 16);
  *(uint4*)(o + i * 4) = ov;
}

// ---------- f32 (R x C) -> bf16 transposed (C x R) ----------
__global__ void transpose3_to_bf16(const float* __restrict__ in0,
                                   const float* __restrict__ in1,
                                   const float* __restrict__ in2,
                                   unsigned short* __restrict__ out,
                                   int R, int C) {
  const float* in = (blockIdx.z == 0) ? in0 : (blockIdx.z == 1) ? in1 : in2;
  unsigned short* o = out + (size_t)blockIdx.z * ((size_t)R * C);
  __shared__ float tile[32][33];
  int c0 = blockIdx.x * 32, r0 = blockIdx.y * 32;
  int tx = threadIdx.x, ty = threadIdx.y;   // 32 x 8
  #pragma unroll
  for (int rr = 0; rr < 32; rr += 8)
    tile[ty + rr][tx] = in[(size_t)(r0 + ty + rr) * C + c0 + tx];
  __syncthreads();
  #pragma unroll
  for (int rr = 0; rr < 32; rr += 8)
    o[(size_t)(c0 + ty + rr) * R + r0 + tx] = f2bf(tile[tx][ty + rr]);
}

__global__ void transpose_to_bf16(const float* __restrict__ in,
                                  unsigned short* __restrict__ out,
                                  int R, int C) {
  __shared__ float tile[32][33];
  int c0 = blockIdx.x * 32, r0 = blockIdx.y * 32;
  int tx = threadIdx.x, ty = threadIdx.y;
  #pragma unroll
  for (int rr = 0; rr < 32; rr += 8)
    tile[ty + rr][tx] = in[(size_t)(r0 + ty + rr) * C + c0 + tx];
  __syncthreads();
  #pragma unroll
  for (int rr = 0; rr < 32; rr += 8)
    out[(size_t)(c0 + ty + rr) * R + r0 + tx] = f2bf(tile[tx][ty + rr]);
}

// ---------- 256x256 8-wave GEMM, BK=32 TRIPLE-buffer, depth-2 prefetch ----------
// Optional DUAL: second half of n-groups processes (A2,Bt2)->Cout2.
template <int NK, int NN, bool PARTIAL, bool DUAL>
__global__ __launch_bounds__(512, 1) void gemm_tb(
    const unsigned short* __restrict__ A,
    const unsigned short* __restrict__ Bt,
    const float* __restrict__ bias,
    void* __restrict__ Cout,
    const unsigned short* __restrict__ A2,
    const unsigned short* __restrict__ Bt2,
    const float* __restrict__ bias2,
    void* __restrict__ Cout2,
    int Mt, int NtG, int KC, int Kfull) {
  constexpr int TT = NK * NN;
  static_assert(TT >= 4, "need >=4 tiles");
  __shared__ unsigned short lds[3 * 2 * 256 * 32];   // 98304 B

  const int nwg = Mt * NtG * KC;
  const int cpx = nwg >> 3;
  const int bid = blockIdx.x;
  const int nb = (bid & 7) * cpx + (bid >> 3);       // bijective XCD swizzle
  const int kc = nb / (Mt * NtG);
  const int r2 = nb % (Mt * NtG);
  const int bm = r2 / NtG;
  const int ng = r2 % NtG;
  const int half = NtG >> 1;
  const int mat = DUAL ? (ng >= half ? 1 : 0) : 0;
  const int ngm = DUAL ? (mat ? ng - half : ng) : ng;
  const int N = (DUAL ? half : NtG) * NN * 256;
  const size_t koff = (size_t)kc * (NK * 32);

  const unsigned short* Asrc = (DUAL && mat) ? A2 : A;
  const unsigned short* Bsrc = (DUAL && mat) ? Bt2 : Bt;
  const float* biasd = (DUAL && mat) ? bias2 : bias;
  void* Cd = (DUAL && mat) ? Cout2 : Cout;

  const int tid = threadIdx.x;
  const int wv = tid >> 6, ln = tid & 63;
  const int wm = wv >> 2, wn = wv & 3;     // 2 M-waves x 4 N-waves

  f32x4 acc[8][4] = {};
  bf16x8 af[8];
  bf16x8 bfb[4];

  auto stage_tile = [&](int tt, char* dst) {
    const int kt = tt % NK;
    const int bnn = ngm * NN + tt / NK;
    #pragma unroll
    for (int j = 0; j < 2; ++j) {
      const int lr = j * 128 + wv * 16 + (ln >> 2);
      const int srcslot = (ln & 3) ^ ((lr >> 1) & 3);
      async_copy16(dst + (j * 128 + wv * 16) * 64 + ln * 16,
                   Asrc + (size_t)(bm * 256 + lr) * Kfull + koff + kt * 32 + srcslot * 8);
      async_copy16(dst + 16384 + (j * 128 + wv * 16) * 64 + ln * 16,
                   Bsrc + (size_t)(bnn * 256 + lr) * Kfull + koff + kt * 32 + srcslot * 8);
    }
  };
  auto load_frags = [&](const char* buf) {
    const int kq = ln >> 4;
    #pragma unroll
    for (int f = 0; f < 8; ++f) {
      const int lr = wm * 128 + f * 16 + (ln & 15);
      af[f] = *(const bf16x8*)(buf + lr * 64 + ((kq ^ ((lr >> 1) & 3)) * 16));
    }
    #pragma unroll
    for (int g = 0; g < 4; ++g) {
      const int lr = wn * 64 + g * 16 + (ln & 15);
      bfb[g] = *(const bf16x8*)(buf + 16384 + lr * 64 + ((kq ^ ((lr >> 1) & 3)) * 16));
    }
  };
  auto epilogue = [&](int nt) {
    const int m0 = bm * 256 + wm * 128 + (ln & 15);
    const int n0 = (ngm * NN + nt) * 256 + wn * 64 + ((ln >> 4) << 2);
    if (PARTIAL) {
      float* Cp = (float*)Cd + (size_t)kc * ((size_t)Mt * 256) * N;
      #pragma unroll
      for (int f = 0; f < 8; ++f) {
        const int row = m0 + f * 16;
        #pragma unroll
        for (int g = 0; g < 4; ++g)
          *(f32x4*)(Cp + (size_t)row * N + n0 + g * 16) = acc[f][g];
      }
    } else {
      unsigned short* C = (unsigned short*)Cd;
      #pragma unroll
      for (int f = 0; f < 8; ++f) {
        const int row = m0 + f * 16;
        #pragma unroll
        for (int g = 0; g < 4; ++g) {
          const int col = n0 + g * 16;
          float4 bv = *(const float4*)(biasd + col);
          uint2 o;
          o.x = f2bf(acc[f][g][0] + bv.x) | ((uint32_t)f2bf(acc[f][g][1] + bv.y) << 16);
          o.y = f2bf(acc[f][g][2] + bv.z) | ((uint32_t)f2bf(acc[f][g][3] + bv.w) << 16);
          *(uint2*)(C + (size_t)row * N + col) = o;
        }
      }
    }
    #pragma unroll
    for (int f = 0; f < 8; ++f)
      #pragma unroll
      for (int g = 0; g < 4; ++g)
        acc[f][g] = (f32x4){0.f, 0.f, 0.f, 0.f};
  };

  char* b0 = (char*)lds;
  char* b1 = (char*)lds + 32768;
  char* b2 = (char*)lds + 65536;

  stage_tile(0, b0);
  stage_tile(1, b1);
  asm volatile("s_waitcnt vmcnt(4)" ::: "memory");
  __builtin_amdgcn_sched_barrier(0);
  __builtin_amdgcn_s_barrier();

  for (int t = 0; t < TT; ++t) {
    if (t + 2 < TT) stage_tile(t + 2, b2);
    load_frags(b0);
    __builtin_amdgcn_s_setprio(1);
    #pragma unroll
    for (int f = 0; f < 8; ++f)
      #pragma unroll
      for (int g = 0; g < 4; ++g)
        acc[f][g] = __builtin_amdgcn_mfma_f32_16x16x32_bf16(
            bfb[g], af[f], acc[f][g], 0, 0, 0);
    __builtin_amdgcn_s_setprio(0);
    __builtin_amdgcn_sched_barrier(0);
    if (t + 2 < TT) {
      asm volatile("s_waitcnt vmcnt(4)" ::: "memory");   // stage(t+1) complete
    } else if (t + 1 < TT) {
      asm volatile("s_waitcnt vmcnt(0)" ::: "memory");
    }
    __builtin_amdgcn_s_barrier();
    if ((t + 1) % NK == 0) epilogue(t / NK);
    char* tmp = b0; b0 = b1; b1 = b2; b2 = tmp;          // rotate buffers
  }
}

// ---------- reduce 4 f32 partials + bias -> out ----------
__global__ void reduce4_bias(const float* __restrict__ p,
                             const float* __restrict__ bo,
                             float* __restrict__ out) {
  const size_t S = (size_t)8192 * 512;
  size_t i = ((size_t)blockIdx.x * 256 + threadIdx.x) * 4;
  float4 a = *(const float4*)(p + i);
  float4 b = *(const float4*)(p + S + i);
  float4 c = *(const float4*)(p + 2 * S + i);
  float4 d = *(const float4*)(p + 3 * S + i);
  float4 bb = *(const float4*)(bo + (int)(i & 511));
  float4 o;
  o.x = a.x + b.x + c.x + d.x + bb.x;
  o.y = a.y + b.y + c.y + d.y + bb.y;
  o.z = a.z + b.z + c.z + d.z + bb.z;
  o.w = a.w + b.w + c.w + d.w + bb.w;
  *(float4*)(out + i) = o;
}

// ---------- MFMA energy + mask + softmax -> P (f32, 8192 x 64) ----------
__global__ __launch_bounds__(256) void energy_mfma(
    const unsigned short* __restrict__ Q,
    const unsigned short* __restrict__ Kb,
    const int* __restrict__ mask,
    float* __restrict__ P) {
  const int wave = threadIdx.x >> 6, ln = threadIdx.x & 63;
  const int t2 = (blockIdx.x * 4 + wave) * 2;
  const int r16 = ln & 15;
  const int g = ln >> 4;
  const size_t rowoff = (size_t)(t2 + (r16 >> 3)) * 4096 + (r16 & 7) * 512 + g * 8;
  const unsigned short* qb = Q + rowoff;
  const unsigned short* kb = Kb + rowoff;

  f32x4 acc = {};
  #pragma unroll
  for (int s = 0; s < 16; ++s) {
    bf16x8 qf = *(const bf16x8*)(qb + s * 32);
    bf16x8 kf = *(const bf16x8*)(kb + s * 32);
    acc = __builtin_amdgcn_mfma_f32_16x16x32_bf16(qf, kf, acc, 0, 0, 0);
  }

  const int ct = r16 >> 3, j = r16 & 7;
  const bool valid = ((g >> 1) == ct);
  const int tok = t2 + ct;
  float pv[4];
  #pragma unroll
  for (int r = 0; r < 4; ++r) {
    const int i = (g & 1) * 4 + r;
    float e = acc[r] * 0.044194173824159216f;          // 1/sqrt(512)
    int mk = 1;
    if (valid) mk = mask[(size_t)tok * 64 + i * 8 + j];
    if (mk == 0) e = -1e30f;
    float m = e;
    m = fmaxf(m, __shfl_xor(m, 1, 64));
    m = fmaxf(m, __shfl_xor(m, 2, 64));
    m = fmaxf(m, __shfl_xor(m, 4, 64));
    float p = __expf(e - m);
    float sum = p;
    sum += __shfl_xor(sum, 1, 64);
    sum += __shfl_xor(sum, 2, 64);
    sum += __shfl_xor(sum, 4, 64);
    pv[r] = p / sum;
  }
  if (valid) {
    #pragma unroll
    for (int r = 0; r < 4; ++r) {
      const int i = (g & 1) * 4 + r;
      P[(size_t)tok * 64 + i * 8 + j] = pv[r];
    }
  }
}

// ---------- PV: out2 rows in the (B,H,L,E)->(B,L,H*E) reshaped layout ----------
__global__ __launch_bounds__(256) void pv_kernel(
    const float* __restrict__ P,
    const unsigned short* __restrict__ Vb,
    unsigned short* __restrict__ out2) {
  const int wave = threadIdx.x >> 6, lane = threadIdx.x & 63;
  const int t = blockIdx.x * 4 + wave;
  const unsigned short* Vr = Vb + (size_t)t * 4096;
  float att = P[(size_t)t * 64 + lane];

  uint4 v4[8];
  #pragma unroll
  for (int jj = 0; jj < 8; ++jj)
    v4[jj] = *(const uint4*)(Vr + jj * 512 + lane * 8);

  const int nb = t >> 11, l = t & 2047;
  const size_t tok_base = (size_t)nb * 8388608 + (size_t)(l >> 3) * 4096 +
                          (size_t)(l & 7) * 512 + lane * 8;
  #pragma unroll
  for (int hh = 0; hh < 8; ++hh) {
    float accv[8] = {0.f, 0.f, 0.f, 0.f, 0.f, 0.f, 0.f, 0.f};
    #pragma unroll
    for (int jj = 0; jj < 8; ++jj) {
      float a = __shfl(att, hh * 8 + jj, 64);
      accv[0] += a * bflo(v4[jj].x); accv[1] += a * bfhi(v4[jj].x);
      accv[2] += a * bflo(v4[jj].y); accv[3] += a * bfhi(v4[jj].y);
      accv[4] += a * bflo(v4[jj].z); accv[5] += a * bfhi(v4[jj].z);
      accv[6] += a * bflo(v4[jj].w); accv[7] += a * bfhi(v4[jj].w);
    }
    uint4 o;
    o.x = f2bf(accv[0]) | ((uint32_t)f2bf(accv[1]) << 16);
    o.y = f2bf(accv[2]) | ((uint32_t)f2bf(accv[3]) << 16);
    o.z = f2bf(accv[4]) | ((uint32_t)f2bf(accv[5]) << 16);
    o.w = f2bf(accv[6]) | ((uint32_t)f2bf(accv[7]) << 16);
    *(uint4*)(out2 + tok_base + (size_t)hh * 1048576) = o;
  }
}

// ---------- launch ----------
extern "C" void kernel_launch(void* const* d_in, const int* in_sizes, int n_in,
                              void* d_out, int out_size, void* d_ws, size_t ws_size,
                              hipStream_t stream) {
  const float* values  = (const float*)d_in[0];
  const float* keys    = (const float*)d_in[1];
  const float* queries = (const float*)d_in[2];
  const int*   mask    = (const int*)d_in[3];
  const float* Wv = (const float*)d_in[4];
  const float* bv = (const float*)d_in[5];
  const float* Wk = (const float*)d_in[6];
  const float* bk = (const float*)d_in[7];
  const float* Wq = (const float*)d_in[8];
  const float* bq = (const float*)d_in[9];
  const float* Wo = (const float*)d_in[10];
  const float* bo = (const float*)d_in[11];

  unsigned short* xv  = (unsigned short*)d_ws;            // 8192*512 x3 (v,k,q)
  unsigned short* xk  = xv + 8192 * 512;
  unsigned short* xq  = xk + 8192 * 512;
  unsigned short* Wvt = xq + 8192 * 512;                  // 4096*512 x3 (v,k,q)
  unsigned short* Wkt = Wvt + 4096 * 512;
  unsigned short* Wqt = Wkt + 4096 * 512;
  unsigned short* Wot = Wqt + 4096 * 512;                 // 512*4096 (N x K)
  float*          P   = (float*)(Wot + 4096 * 512);       // 8192*64 f32
  unsigned short* bufA = (unsigned short*)(P + 8192 * 64); // 8192*4096 bf16
  unsigned short* bufB = bufA + (size_t)8192 * 4096;       // 8192*4096 bf16

  const int nx = 8192 * 512;
  cvt3_f32_bf16<<<dim3(nx / 8 / 256, 3), 256, 0, stream>>>(
      values, keys, queries, (uint32_t*)xv, nx);

  transpose3_to_bf16<<<dim3(4096 / 32, 512 / 32, 3), dim3(32, 8), 0, stream>>>(
      Wv, Wk, Wq, Wvt, 512, 4096);
  transpose_to_bf16<<<dim3(512 / 32, 4096 / 32), dim3(32, 8), 0, stream>>>(
      Wo, Wot, 4096, 512);

  // fused Q+K projections: gemm_tb DUAL, NK=16 (K=512/32), NN=4, NtG=8, 256 blocks
  gemm_tb<16, 4, false, true><<<256, 512, 0, stream>>>(
      xq, Wqt, bq, bufA, xk, Wkt, bk, bufB, 32, 8, 1, 512);

  // energy + softmax -> P  (Q, K dead afterwards)
  energy_mfma<<<8192 / 8, 256, 0, stream>>>(bufA, bufB, mask, P);

  // V -> bufA (BK=32 triple-buffer counted-vmcnt)
  gemm_tb<16, 2, false, false><<<256, 512, 0, stream>>>(
      xv, Wvt, bv, bufA, nullptr, nullptr, nullptr, nullptr, 32, 8, 1, 512);

  // PV -> bufB (overwrites K)
  pv_kernel<<<8192 / 4, 256, 0, stream>>>(P, bufA, bufB);

  // final: split-K=4 f32 partials via gemm_tb (NK=32 per 1024-K chunk)
  gemm_tb<32, 1, true, false><<<256, 512, 0, stream>>>(
      bufB, Wot, nullptr, (float*)bufA, nullptr, nullptr, nullptr, nullptr,
      32, 2, 4, 4096);
  reduce4_bias<<<4096, 256, 0, stream>>>((float*)bufA, bo, (float*)d_out);
}

// Round 21
// 259.132 us; speedup vs baseline: 1.0224x; 1.0224x over previous
//
#include <hip/hip_runtime.h>
#include <stdint.h>

typedef __attribute__((ext_vector_type(4))) float f32x4;
typedef __attribute__((ext_vector_type(8))) __bf16 bf16x8;

// ---------- helpers ----------
__device__ __forceinline__ unsigned short f2bf(float f) {
  union { float f; uint32_t u; } v; v.f = f;
  uint32_t u = v.u;
  return (unsigned short)((u + 0x7FFFu + ((u >> 16) & 1u)) >> 16);
}
__device__ __forceinline__ float bflo(uint32_t u) {
  union { uint32_t u; float f; } v; v.u = u << 16; return v.f;
}
__device__ __forceinline__ float bfhi(uint32_t u) {
  union { uint32_t u; float f; } v; v.u = u & 0xffff0000u; return v.f;
}

__device__ __forceinline__ void async_copy16(void* lds, const void* g) {
  __builtin_amdgcn_global_load_lds(
      (const __attribute__((address_space(1))) void*)g,
      (__attribute__((address_space(3))) void*)lds,
      16, 0, 0);
}

// ---------- f32 -> bf16 convert: 3 tensors in one launch ----------
__global__ void cvt3_f32_bf16(const float* __restrict__ in0,
                              const float* __restrict__ in1,
                              const float* __restrict__ in2,
                              uint32_t* __restrict__ out, int n) {
  const float* in = (blockIdx.y == 0) ? in0 : (blockIdx.y == 1) ? in1 : in2;
  uint32_t* o = out + (size_t)blockIdx.y * (n / 2);   // n bf16 = n/2 words
  int i = blockIdx.x * blockDim.x + threadIdx.x;
  int idx = i * 8;
  if (idx >= n) return;
  float4 a = *(const float4*)(in + idx);
  float4 b = *(const float4*)(in + idx + 4);
  uint4 ov;
  ov.x = f2bf(a.x) | ((uint32_t)f2bf(a.y) << 16);
  ov.y = f2bf(a.z) | ((uint32_t)f2bf(a.w) << 16);
  ov.z = f2bf(b.x) | ((uint32_t)f2bf(b.y) << 16);
  ov.w = f2bf(b.z) | ((uint32_t)f2bf(b.w) << 16);
  *(uint4*)(o + i * 4) = ov;
}

// ---------- f32 (R x C) -> bf16 transposed (C x R) ----------
__global__ void transpose3_to_bf16(const float* __restrict__ in0,
                                   const float* __restrict__ in1,
                                   const float* __restrict__ in2,
                                   unsigned short* __restrict__ out,
                                   int R, int C) {
  const float* in = (blockIdx.z == 0) ? in0 : (blockIdx.z == 1) ? in1 : in2;
  unsigned short* o = out + (size_t)blockIdx.z * ((size_t)R * C);
  __shared__ float tile[32][33];
  int c0 = blockIdx.x * 32, r0 = blockIdx.y * 32;
  int tx = threadIdx.x, ty = threadIdx.y;   // 32 x 8
  #pragma unroll
  for (int rr = 0; rr < 32; rr += 8)
    tile[ty + rr][tx] = in[(size_t)(r0 + ty + rr) * C + c0 + tx];
  __syncthreads();
  #pragma unroll
  for (int rr = 0; rr < 32; rr += 8)
    o[(size_t)(c0 + ty + rr) * R + r0 + tx] = f2bf(tile[tx][ty + rr]);
}

__global__ void transpose_to_bf16(const float* __restrict__ in,
                                  unsigned short* __restrict__ out,
                                  int R, int C) {
  __shared__ float tile[32][33];
  int c0 = blockIdx.x * 32, r0 = blockIdx.y * 32;
  int tx = threadIdx.x, ty = threadIdx.y;
  #pragma unroll
  for (int rr = 0; rr < 32; rr += 8)
    tile[ty + rr][tx] = in[(size_t)(r0 + ty + rr) * C + c0 + tx];
  __syncthreads();
  #pragma unroll
  for (int rr = 0; rr < 32; rr += 8)
    out[(size_t)(c0 + ty + rr) * R + r0 + tx] = f2bf(tile[tx][ty + rr]);
}

// ---------- 256x256 8-wave GEMM, BK=64 dbuf (QK kernel; parametric DUAL split) ----------
template <int NK, int NN, bool PARTIAL, bool DUAL>
__global__ __launch_bounds__(512, 2) void gemm256(
    const unsigned short* __restrict__ A,
    const unsigned short* __restrict__ Bt,
    const float* __restrict__ bias,
    void* __restrict__ Cout,
    const unsigned short* __restrict__ A2,
    const unsigned short* __restrict__ Bt2,
    const float* __restrict__ bias2,
    void* __restrict__ Cout2,
    int Mt, int NtG, int KC, int Kfull) {
  constexpr int TT = NK * NN;
  static_assert(TT >= 4 && (TT % 2) == 0, "need even TT >= 4");
  __shared__ unsigned short lds[2 * 2 * 256 * 64];   // 131072 B

  const int nwg = Mt * NtG * KC;
  const int cpx = nwg >> 3;
  const int bid = blockIdx.x;
  const int nb = (bid & 7) * cpx + (bid >> 3);       // bijective XCD swizzle
  const int kc = nb / (Mt * NtG);
  const int r2 = nb % (Mt * NtG);
  const int bm = r2 / NtG;
  const int ng = r2 % NtG;
  const int half = NtG >> 1;                         // per-matrix n-group count
  const int mat = DUAL ? (ng >= half ? 1 : 0) : 0;
  const int ngm = DUAL ? (mat ? ng - half : ng) : ng;
  const int N = (DUAL ? half : NtG) * NN * 256;
  const size_t koff = (size_t)kc * (NK * 64);

  const unsigned short* Asrc = (DUAL && mat) ? A2 : A;
  const unsigned short* Bsrc = (DUAL && mat) ? Bt2 : Bt;
  const float* biasd = (DUAL && mat) ? bias2 : bias;
  void* Cd = (DUAL && mat) ? Cout2 : Cout;

  const int tid = threadIdx.x;
  const int wv = tid >> 6, ln = tid & 63;
  const int wm = wv >> 2, wn = wv & 3;     // 2 M-waves x 4 N-waves

  f32x4 acc[8][4] = {};
  bf16x8 af[4][2];
  bf16x8 bfb[2][2];

  char* const lds0 = (char*)lds;
  char* const lds1 = (char*)lds + 65536;

  auto stage_tile = [&](int tt, char* dst) {
    const int kt = tt % NK;
    const int bnn = ngm * NN + tt / NK;
    #pragma unroll
    for (int i = 0; i < 4; ++i) {
      const int rb = i * 64 + wv * 8;
      const int row = rb + (ln >> 3);
      const int kcs = (ln & 7) ^ (row & 7);
      async_copy16(dst + rb * 128,
                   Asrc + (size_t)(bm * 256 + row) * Kfull + koff + kt * 64 + kcs * 8);
      async_copy16(dst + 32768 + rb * 128,
                   Bsrc + (size_t)(bnn * 256 + row) * Kfull + koff + kt * 64 + kcs * 8);
    }
  };
  auto load_af = [&](int mh, const char* buf) {
    #pragma unroll
    for (int f = 0; f < 4; ++f) {
      const int lr = wm * 128 + (mh * 4 + f) * 16 + (ln & 15);
      #pragma unroll
      for (int s = 0; s < 2; ++s) {
        const int kq = s * 4 + (ln >> 4);
        af[f][s] = *(const bf16x8*)(buf + lr * 128 + ((kq ^ (lr & 7)) * 16));
      }
    }
  };
  auto load_bf = [&](int nh, const char* buf) {
    #pragma unroll
    for (int gq = 0; gq < 2; ++gq) {
      const int lr = wn * 64 + (nh * 2 + gq) * 16 + (ln & 15);
      #pragma unroll
      for (int s = 0; s < 2; ++s) {
        const int kq = s * 4 + (ln >> 4);
        bfb[gq][s] =
            *(const bf16x8*)(buf + 32768 + lr * 128 + ((kq ^ (lr & 7)) * 16));
      }
    }
  };
  auto mfma_quad = [&](int mh, int nh) {
    __builtin_amdgcn_s_setprio(1);
    #pragma unroll
    for (int s = 0; s < 2; ++s)
      #pragma unroll
      for (int f = 0; f < 4; ++f)
        #pragma unroll
        for (int gq = 0; gq < 2; ++gq)
          acc[mh * 4 + f][nh * 2 + gq] = __builtin_amdgcn_mfma_f32_16x16x32_bf16(
              bfb[gq][s], af[f][s], acc[mh * 4 + f][nh * 2 + gq], 0, 0, 0);
    __builtin_amdgcn_s_setprio(0);
  };
  auto epilogue = [&](int nt) {
    const int m0 = bm * 256 + wm * 128 + (ln & 15);
    const int n0 = (ngm * NN + nt) * 256 + wn * 64 + ((ln >> 4) << 2);
    if (PARTIAL) {
      float* Cp = (float*)Cd + (size_t)kc * ((size_t)Mt * 256) * N;
      #pragma unroll
      for (int f = 0; f < 8; ++f) {
        const int row = m0 + f * 16;
        #pragma unroll
        for (int g = 0; g < 4; ++g)
          *(f32x4*)(Cp + (size_t)row * N + n0 + g * 16) = acc[f][g];
      }
    } else {
      unsigned short* C = (unsigned short*)Cd;
      #pragma unroll
      for (int f = 0; f < 8; ++f) {
        const int row = m0 + f * 16;
        #pragma unroll
        for (int g = 0; g < 4; ++g) {
          const int col = n0 + g * 16;
          float4 bv = *(const float4*)(biasd + col);
          uint2 o;
          o.x = f2bf(acc[f][g][0] + bv.x) | ((uint32_t)f2bf(acc[f][g][1] + bv.y) << 16);
          o.y = f2bf(acc[f][g][2] + bv.z) | ((uint32_t)f2bf(acc[f][g][3] + bv.w) << 16);
          *(uint2*)(C + (size_t)row * N + col) = o;
        }
      }
    }
    #pragma unroll
    for (int f = 0; f < 8; ++f)
      #pragma unroll
      for (int g = 0; g < 4; ++g)
        acc[f][g] = (f32x4){0.f, 0.f, 0.f, 0.f};
  };

  auto tile_body = [&](int tau, const char* buf, char* obuf) {
    if (tau + 1 < TT) stage_tile(tau + 1, obuf);
    load_af(0, buf); load_bf(0, buf);
    mfma_quad(0, 0);
    __builtin_amdgcn_sched_barrier(0);
    load_bf(1, buf);
    mfma_quad(0, 1);
    __builtin_amdgcn_sched_barrier(0);
    load_af(1, buf);
    mfma_quad(1, 1);
    __builtin_amdgcn_sched_barrier(0);
    load_bf(0, buf);
    mfma_quad(1, 0);
    __builtin_amdgcn_sched_barrier(0);
    if (tau + 1 < TT)
      asm volatile("s_waitcnt vmcnt(0)" ::: "memory");
    __builtin_amdgcn_s_barrier();
    if ((tau + 1) % NK == 0) epilogue(tau / NK);
  };

  stage_tile(0, lds0);
  asm volatile("s_waitcnt vmcnt(0)" ::: "memory");
  __builtin_amdgcn_sched_barrier(0);
  __builtin_amdgcn_s_barrier();

  for (int it = 0; it < TT / 2; ++it) {
    tile_body(2 * it,     lds0, lds1);
    tile_body(2 * it + 1, lds1, lds0);
  }
}

// ---------- 256x256 8-wave GEMM, BK=32 TRIPLE-buffer, prefetch depth 2 ----------
template <int NK, int NN, bool PARTIAL>
__global__ __launch_bounds__(512, 1) void gemm_tb(
    const unsigned short* __restrict__ A,
    const unsigned short* __restrict__ Bt,
    const float* __restrict__ bias,
    void* __restrict__ Cout,
    int Mt, int NtG, int KC, int Kfull) {
  constexpr int TT = NK * NN;
  static_assert(TT >= 4, "need >=4 tiles");
  __shared__ unsigned short lds[3 * 2 * 256 * 32];   // 98304 B

  const int nwg = Mt * NtG * KC;
  const int cpx = nwg >> 3;
  const int bid = blockIdx.x;
  const int nb = (bid & 7) * cpx + (bid >> 3);       // bijective XCD swizzle
  const int kc = nb / (Mt * NtG);
  const int r2 = nb % (Mt * NtG);
  const int bm = r2 / NtG;
  const int ng = r2 % NtG;
  const int N = NtG * NN * 256;
  const size_t koff = (size_t)kc * (NK * 32);

  const int tid = threadIdx.x;
  const int wv = tid >> 6, ln = tid & 63;
  const int wm = wv >> 2, wn = wv & 3;     // 2 M-waves x 4 N-waves

  f32x4 acc[8][4] = {};
  bf16x8 af[8];
  bf16x8 bfb[4];

  auto stage_tile = [&](int tt, char* dst) {
    const int kt = tt % NK;
    const int bnn = ng * NN + tt / NK;
    #pragma unroll
    for (int j = 0; j < 2; ++j) {
      const int lr = j * 128 + wv * 16 + (ln >> 2);
      const int srcslot = (ln & 3) ^ ((lr >> 1) & 3);
      async_copy16(dst + (j * 128 + wv * 16) * 64 + ln * 16,
                   A + (size_t)(bm * 256 + lr) * Kfull + koff + kt * 32 + srcslot * 8);
      async_copy16(dst + 16384 + (j * 128 + wv * 16) * 64 + ln * 16,
                   Bt + (size_t)(bnn * 256 + lr) * Kfull + koff + kt * 32 + srcslot * 8);
    }
  };
  auto load_frags = [&](const char* buf) {
    const int kq = ln >> 4;
    #pragma unroll
    for (int f = 0; f < 8; ++f) {
      const int lr = wm * 128 + f * 16 + (ln & 15);
      af[f] = *(const bf16x8*)(buf + lr * 64 + ((kq ^ ((lr >> 1) & 3)) * 16));
    }
    #pragma unroll
    for (int g = 0; g < 4; ++g) {
      const int lr = wn * 64 + g * 16 + (ln & 15);
      bfb[g] = *(const bf16x8*)(buf + 16384 + lr * 64 + ((kq ^ ((lr >> 1) & 3)) * 16));
    }
  };
  auto epilogue = [&](int nt) {
    const int m0 = bm * 256 + wm * 128 + (ln & 15);
    const int n0 = (ng * NN + nt) * 256 + wn * 64 + ((ln >> 4) << 2);
    if (PARTIAL) {
      float* Cp = (float*)Cout + (size_t)kc * ((size_t)Mt * 256) * N;
      #pragma unroll
      for (int f = 0; f < 8; ++f) {
        const int row = m0 + f * 16;
        #pragma unroll
        for (int g = 0; g < 4; ++g)
          *(f32x4*)(Cp + (size_t)row * N + n0 + g * 16) = acc[f][g];
      }
    } else {
      unsigned short* C = (unsigned short*)Cout;
      #pragma unroll
      for (int f = 0; f < 8; ++f) {
        const int row = m0 + f * 16;
        #pragma unroll
        for (int g = 0; g < 4; ++g) {
          const int col = n0 + g * 16;
          float4 bv = *(const float4*)(bias + col);
          uint2 o;
          o.x = f2bf(acc[f][g][0] + bv.x) | ((uint32_t)f2bf(acc[f][g][1] + bv.y) << 16);
          o.y = f2bf(acc[f][g][2] + bv.z) | ((uint32_t)f2bf(acc[f][g][3] + bv.w) << 16);
          *(uint2*)(C + (size_t)row * N + col) = o;
        }
      }
    }
    #pragma unroll
    for (int f = 0; f < 8; ++f)
      #pragma unroll
      for (int g = 0; g < 4; ++g)
        acc[f][g] = (f32x4){0.f, 0.f, 0.f, 0.f};
  };

  char* b0 = (char*)lds;
  char* b1 = (char*)lds + 32768;
  char* b2 = (char*)lds + 65536;

  stage_tile(0, b0);
  stage_tile(1, b1);
  asm volatile("s_waitcnt vmcnt(4)" ::: "memory");
  __builtin_amdgcn_sched_barrier(0);
  __builtin_amdgcn_s_barrier();

  for (int t = 0; t < TT; ++t) {
    if (t + 2 < TT) stage_tile(t + 2, b2);
    load_frags(b0);
    __builtin_amdgcn_s_setprio(1);
    #pragma unroll
    for (int f = 0; f < 8; ++f)
      #pragma unroll
      for (int g = 0; g < 4; ++g)
        acc[f][g] = __builtin_amdgcn_mfma_f32_16x16x32_bf16(
            bfb[g], af[f], acc[f][g], 0, 0, 0);
    __builtin_amdgcn_s_setprio(0);
    __builtin_amdgcn_sched_barrier(0);
    if (t + 2 < TT) {
      asm volatile("s_waitcnt vmcnt(4)" ::: "memory");
    } else if (t + 1 < TT) {
      asm volatile("s_waitcnt vmcnt(0)" ::: "memory");
    }
    __builtin_amdgcn_s_barrier();
    if ((t + 1) % NK == 0) epilogue(t / NK);
    char* tmp = b0; b0 = b1; b1 = b2; b2 = tmp;
  }
}

// ---------- reduce 4 f32 partials + bias -> out ----------
__global__ void reduce4_bias(const float* __restrict__ p,
                             const float* __restrict__ bo,
                             float* __restrict__ out) {
  const size_t S = (size_t)8192 * 512;
  size_t i = ((size_t)blockIdx.x * 256 + threadIdx.x) * 4;
  float4 a = *(const float4*)(p + i);
  float4 b = *(const float4*)(p + S + i);
  float4 c = *(const float4*)(p + 2 * S + i);
  float4 d = *(const float4*)(p + 3 * S + i);
  float4 bb = *(const float4*)(bo + (int)(i & 511));
  float4 o;
  o.x = a.x + b.x + c.x + d.x + bb.x;
  o.y = a.y + b.y + c.y + d.y + bb.y;
  o.z = a.z + b.z + c.z + d.z + bb.z;
  o.w = a.w + b.w + c.w + d.w + bb.w;
  *(float4*)(out + i) = o;
}

// ---------- MFMA energy + mask + softmax -> P (f32, 8192 x 64) ----------
__global__ __launch_bounds__(256) void energy_mfma(
    const unsigned short* __restrict__ Q,
    const unsigned short* __restrict__ Kb,
    const int* __restrict__ mask,
    float* __restrict__ P) {
  const int wave = threadIdx.x >> 6, ln = threadIdx.x & 63;
  const int t2 = (blockIdx.x * 4 + wave) * 2;
  const int r16 = ln & 15;
  const int g = ln >> 4;
  const size_t rowoff = (size_t)(t2 + (r16 >> 3)) * 4096 + (r16 & 7) * 512 + g * 8;
  const unsigned short* qb = Q + rowoff;
  const unsigned short* kb = Kb + rowoff;

  f32x4 acc = {};
  #pragma unroll
  for (int s = 0; s < 16; ++s) {
    bf16x8 qf = *(const bf16x8*)(qb + s * 32);
    bf16x8 kf = *(const bf16x8*)(kb + s * 32);
    acc = __builtin_amdgcn_mfma_f32_16x16x32_bf16(qf, kf, acc, 0, 0, 0);
  }

  const int ct = r16 >> 3, j = r16 & 7;
  const bool valid = ((g >> 1) == ct);
  const int tok = t2 + ct;
  float pv[4];
  #pragma unroll
  for (int r = 0; r < 4; ++r) {
    const int i = (g & 1) * 4 + r;
    float e = acc[r] * 0.044194173824159216f;          // 1/sqrt(512)
    int mk = 1;
    if (valid) mk = mask[(size_t)tok * 64 + i * 8 + j];
    if (mk == 0) e = -1e30f;
    float m = e;
    m = fmaxf(m, __shfl_xor(m, 1, 64));
    m = fmaxf(m, __shfl_xor(m, 2, 64));
    m = fmaxf(m, __shfl_xor(m, 4, 64));
    float p = __expf(e - m);
    float sum = p;
    sum += __shfl_xor(sum, 1, 64);
    sum += __shfl_xor(sum, 2, 64);
    sum += __shfl_xor(sum, 4, 64);
    pv[r] = p / sum;
  }
  if (valid) {
    #pragma unroll
    for (int r = 0; r < 4; ++r) {
      const int i = (g & 1) * 4 + r;
      P[(size_t)tok * 64 + i * 8 + j] = pv[r];
    }
  }
}

// ---------- PV: out2 rows in the (B,H,L,E)->(B,L,H*E) reshaped layout ----------
__global__ __launch_bounds__(256) void pv_kernel(
    const float* __restrict__ P,
    const unsigned short* __restrict__ Vb,
    unsigned short* __restrict__ out2) {
  const int wave = threadIdx.x >> 6, lane = threadIdx.x & 63;
  const int t = blockIdx.x * 4 + wave;
  const unsigned short* Vr = Vb + (size_t)t * 4096;
  float att = P[(size_t)t * 64 + lane];

  uint4 v4[8];
  #pragma unroll
  for (int jj = 0; jj < 8; ++jj)
    v4[jj] = *(const uint4*)(Vr + jj * 512 + lane * 8);

  const int nb = t >> 11, l = t & 2047;
  const size_t tok_base = (size_t)nb * 8388608 + (size_t)(l >> 3) * 4096 +
                          (size_t)(l & 7) * 512 + lane * 8;
  #pragma unroll
  for (int hh = 0; hh < 8; ++hh) {
    float accv[8] = {0.f, 0.f, 0.f, 0.f, 0.f, 0.f, 0.f, 0.f};
    #pragma unroll
    for (int jj = 0; jj < 8; ++jj) {
      float a = __shfl(att, hh * 8 + jj, 64);
      accv[0] += a * bflo(v4[jj].x); accv[1] += a * bfhi(v4[jj].x);
      accv[2] += a * bflo(v4[jj].y); accv[3] += a * bfhi(v4[jj].y);
      accv[4] += a * bflo(v4[jj].z); accv[5] += a * bfhi(v4[jj].z);
      accv[6] += a * bflo(v4[jj].w); accv[7] += a * bfhi(v4[jj].w);
    }
    uint4 o;
    o.x = f2bf(accv[0]) | ((uint32_t)f2bf(accv[1]) << 16);
    o.y = f2bf(accv[2]) | ((uint32_t)f2bf(accv[3]) << 16);
    o.z = f2bf(accv[4]) | ((uint32_t)f2bf(accv[5]) << 16);
    o.w = f2bf(accv[6]) | ((uint32_t)f2bf(accv[7]) << 16);
    *(uint4*)(out2 + tok_base + (size_t)hh * 1048576) = o;
  }
}

// ---------- launch ----------
extern "C" void kernel_launch(void* const* d_in, const int* in_sizes, int n_in,
                              void* d_out, int out_size, void* d_ws, size_t ws_size,
                              hipStream_t stream) {
  const float* values  = (const float*)d_in[0];
  const float* keys    = (const float*)d_in[1];
  const float* queries = (const float*)d_in[2];
  const int*   mask    = (const int*)d_in[3];
  const float* Wv = (const float*)d_in[4];
  const float* bv = (const float*)d_in[5];
  const float* Wk = (const float*)d_in[6];
  const float* bk = (const float*)d_in[7];
  const float* Wq = (const float*)d_in[8];
  const float* bq = (const float*)d_in[9];
  const float* Wo = (const float*)d_in[10];
  const float* bo = (const float*)d_in[11];

  unsigned short* xv  = (unsigned short*)d_ws;            // 8192*512 x3 (v,k,q)
  unsigned short* xk  = xv + 8192 * 512;
  unsigned short* xq  = xk + 8192 * 512;
  unsigned short* Wvt = xq + 8192 * 512;                  // 4096*512 x3 (v,k,q)
  unsigned short* Wkt = Wvt + 4096 * 512;
  unsigned short* Wqt = Wkt + 4096 * 512;
  unsigned short* Wot = Wqt + 4096 * 512;                 // 512*4096 (N x K)
  float*          P   = (float*)(Wot + 4096 * 512);       // 8192*64 f32
  unsigned short* bufA = (unsigned short*)(P + 8192 * 64); // 8192*4096 bf16
  unsigned short* bufB = bufA + (size_t)8192 * 4096;       // 8192*4096 bf16

  const int nx = 8192 * 512;
  cvt3_f32_bf16<<<dim3(nx / 8 / 256, 3), 256, 0, stream>>>(
      values, keys, queries, (uint32_t*)xv, nx);

  transpose3_to_bf16<<<dim3(4096 / 32, 512 / 32, 3), dim3(32, 8), 0, stream>>>(
      Wv, Wk, Wq, Wvt, 512, 4096);
  transpose_to_bf16<<<dim3(512 / 32, 4096 / 32), dim3(32, 8), 0, stream>>>(
      Wo, Wot, 4096, 512);

  // fused Q+K projections: NN=4, NtG=8 (4 n-groups per matrix), 256 blocks (1 round)
  gemm256<8, 4, false, true><<<256, 512, 0, stream>>>(
      xq, Wqt, bq, bufA, xk, Wkt, bk, bufB, 32, 8, 1, 512);

  // energy + softmax -> P  (Q, K dead afterwards)
  energy_mfma<<<8192 / 8, 256, 0, stream>>>(bufA, bufB, mask, P);

  // V -> bufA (BK=32 triple-buffer counted-vmcnt)
  gemm_tb<16, 2, false><<<256, 512, 0, stream>>>(
      xv, Wvt, bv, bufA, 32, 8, 1, 512);

  // PV -> bufB (overwrites K)
  pv_kernel<<<8192 / 4, 256, 0, stream>>>(P, bufA, bufB);

  // final: split-K=4 f32 partials via gemm_tb (NK=32 per 1024-K chunk)
  gemm_tb<32, 1, true><<<256, 512, 0, stream>>>(
      bufB, Wot, nullptr, (float*)bufA, 32, 2, 4, 4096);
  reduce4_bias<<<4096, 256, 0, stream>>>((float*)bufA, bo, (float*)d_out);
}

// Round 22
// 255.608 us; speedup vs baseline: 1.0365x; 1.0138x over previous
//
#include <hip/hip_runtime.h>
#include <stdint.h>

typedef __attribute__((ext_vector_type(4))) float f32x4;
typedef __attribute__((ext_vector_type(8))) __bf16 bf16x8;

// ---------- helpers ----------
__device__ __forceinline__ unsigned short f2bf(float f) {
  union { float f; uint32_t u; } v; v.f = f;
  uint32_t u = v.u;
  return (unsigned short)((u + 0x7FFFu + ((u >> 16) & 1u)) >> 16);
}
__device__ __forceinline__ float bflo(uint32_t u) {
  union { uint32_t u; float f; } v; v.u = u << 16; return v.f;
}
__device__ __forceinline__ float bfhi(uint32_t u) {
  union { uint32_t u; float f; } v; v.u = u & 0xffff0000u; return v.f;
}

__device__ __forceinline__ void async_copy16(void* lds, const void* g) {
  __builtin_amdgcn_global_load_lds(
      (const __attribute__((address_space(1))) void*)g,
      (__attribute__((address_space(3))) void*)lds,
      16, 0, 0);
}

// ---------- f32 -> bf16 convert: 3 tensors in one launch ----------
__global__ void cvt3_f32_bf16(const float* __restrict__ in0,
                              const float* __restrict__ in1,
                              const float* __restrict__ in2,
                              uint32_t* __restrict__ out, int n) {
  const float* in = (blockIdx.y == 0) ? in0 : (blockIdx.y == 1) ? in1 : in2;
  uint32_t* o = out + (size_t)blockIdx.y * (n / 2);   // n bf16 = n/2 words
  int i = blockIdx.x * blockDim.x + threadIdx.x;
  int idx = i * 8;
  if (idx >= n) return;
  float4 a = *(const float4*)(in + idx);
  float4 b = *(const float4*)(in + idx + 4);
  uint4 ov;
  ov.x = f2bf(a.x) | ((uint32_t)f2bf(a.y) << 16);
  ov.y = f2bf(a.z) | ((uint32_t)f2bf(a.w) << 16);
  ov.z = f2bf(b.x) | ((uint32_t)f2bf(b.y) << 16);
  ov.w = f2bf(b.z) | ((uint32_t)f2bf(b.w) << 16);
  *(uint4*)(o + i * 4) = ov;
}

// ---------- f32 (R x C) -> bf16 transposed (C x R) ----------
__global__ void transpose3_to_bf16(const float* __restrict__ in0,
                                   const float* __restrict__ in1,
                                   const float* __restrict__ in2,
                                   unsigned short* __restrict__ out,
                                   int R, int C) {
  const float* in = (blockIdx.z == 0) ? in0 : (blockIdx.z == 1) ? in1 : in2;
  unsigned short* o = out + (size_t)blockIdx.z * ((size_t)R * C);
  __shared__ float tile[32][33];
  int c0 = blockIdx.x * 32, r0 = blockIdx.y * 32;
  int tx = threadIdx.x, ty = threadIdx.y;   // 32 x 8
  #pragma unroll
  for (int rr = 0; rr < 32; rr += 8)
    tile[ty + rr][tx] = in[(size_t)(r0 + ty + rr) * C + c0 + tx];
  __syncthreads();
  #pragma unroll
  for (int rr = 0; rr < 32; rr += 8)
    o[(size_t)(c0 + ty + rr) * R + r0 + tx] = f2bf(tile[tx][ty + rr]);
}

__global__ void transpose_to_bf16(const float* __restrict__ in,
                                  unsigned short* __restrict__ out,
                                  int R, int C) {
  __shared__ float tile[32][33];
  int c0 = blockIdx.x * 32, r0 = blockIdx.y * 32;
  int tx = threadIdx.x, ty = threadIdx.y;
  #pragma unroll
  for (int rr = 0; rr < 32; rr += 8)
    tile[ty + rr][tx] = in[(size_t)(r0 + ty + rr) * C + c0 + tx];
  __syncthreads();
  #pragma unroll
  for (int rr = 0; rr < 32; rr += 8)
    out[(size_t)(c0 + ty + rr) * R + r0 + tx] = f2bf(tile[tx][ty + rr]);
}

// ---------- 256x256 8-wave GEMM, BK=64 dbuf (QK kernel; parametric DUAL split) ----------
template <int NK, int NN, bool PARTIAL, bool DUAL>
__global__ __launch_bounds__(512, 2) void gemm256(
    const unsigned short* __restrict__ A,
    const unsigned short* __restrict__ Bt,
    const float* __restrict__ bias,
    void* __restrict__ Cout,
    const unsigned short* __restrict__ A2,
    const unsigned short* __restrict__ Bt2,
    const float* __restrict__ bias2,
    void* __restrict__ Cout2,
    int Mt, int NtG, int KC, int Kfull) {
  constexpr int TT = NK * NN;
  static_assert(TT >= 4 && (TT % 2) == 0, "need even TT >= 4");
  __shared__ unsigned short lds[2 * 2 * 256 * 64];   // 131072 B

  const int nwg = Mt * NtG * KC;
  const int cpx = nwg >> 3;
  const int bid = blockIdx.x;
  const int nb = (bid & 7) * cpx + (bid >> 3);       // bijective XCD swizzle
  const int kc = nb / (Mt * NtG);
  const int r2 = nb % (Mt * NtG);
  const int bm = r2 / NtG;
  const int ng = r2 % NtG;
  const int half = NtG >> 1;                         // per-matrix n-group count
  const int mat = DUAL ? (ng >= half ? 1 : 0) : 0;
  const int ngm = DUAL ? (mat ? ng - half : ng) : ng;
  const int N = (DUAL ? half : NtG) * NN * 256;
  const size_t koff = (size_t)kc * (NK * 64);

  const unsigned short* Asrc = (DUAL && mat) ? A2 : A;
  const unsigned short* Bsrc = (DUAL && mat) ? Bt2 : Bt;
  const float* biasd = (DUAL && mat) ? bias2 : bias;
  void* Cd = (DUAL && mat) ? Cout2 : Cout;

  const int tid = threadIdx.x;
  const int wv = tid >> 6, ln = tid & 63;
  const int wm = wv >> 2, wn = wv & 3;     // 2 M-waves x 4 N-waves

  f32x4 acc[8][4] = {};
  bf16x8 af[4][2];
  bf16x8 bfb[2][2];

  char* const lds0 = (char*)lds;
  char* const lds1 = (char*)lds + 65536;

  auto stage_tile = [&](int tt, char* dst) {
    const int kt = tt % NK;
    const int bnn = ngm * NN + tt / NK;
    #pragma unroll
    for (int i = 0; i < 4; ++i) {
      const int rb = i * 64 + wv * 8;
      const int row = rb + (ln >> 3);
      const int kcs = (ln & 7) ^ (row & 7);
      async_copy16(dst + rb * 128,
                   Asrc + (size_t)(bm * 256 + row) * Kfull + koff + kt * 64 + kcs * 8);
      async_copy16(dst + 32768 + rb * 128,
                   Bsrc + (size_t)(bnn * 256 + row) * Kfull + koff + kt * 64 + kcs * 8);
    }
  };
  auto load_af = [&](int mh, const char* buf) {
    #pragma unroll
    for (int f = 0; f < 4; ++f) {
      const int lr = wm * 128 + (mh * 4 + f) * 16 + (ln & 15);
      #pragma unroll
      for (int s = 0; s < 2; ++s) {
        const int kq = s * 4 + (ln >> 4);
        af[f][s] = *(const bf16x8*)(buf + lr * 128 + ((kq ^ (lr & 7)) * 16));
      }
    }
  };
  auto load_bf = [&](int nh, const char* buf) {
    #pragma unroll
    for (int gq = 0; gq < 2; ++gq) {
      const int lr = wn * 64 + (nh * 2 + gq) * 16 + (ln & 15);
      #pragma unroll
      for (int s = 0; s < 2; ++s) {
        const int kq = s * 4 + (ln >> 4);
        bfb[gq][s] =
            *(const bf16x8*)(buf + 32768 + lr * 128 + ((kq ^ (lr & 7)) * 16));
      }
    }
  };
  auto mfma_quad = [&](int mh, int nh) {
    __builtin_amdgcn_s_setprio(1);
    #pragma unroll
    for (int s = 0; s < 2; ++s)
      #pragma unroll
      for (int f = 0; f < 4; ++f)
        #pragma unroll
        for (int gq = 0; gq < 2; ++gq)
          acc[mh * 4 + f][nh * 2 + gq] = __builtin_amdgcn_mfma_f32_16x16x32_bf16(
              bfb[gq][s], af[f][s], acc[mh * 4 + f][nh * 2 + gq], 0, 0, 0);
    __builtin_amdgcn_s_setprio(0);
  };
  auto epilogue = [&](int nt) {
    const int m0 = bm * 256 + wm * 128 + (ln & 15);
    const int n0 = (ngm * NN + nt) * 256 + wn * 64 + ((ln >> 4) << 2);
    if (PARTIAL) {
      float* Cp = (float*)Cd + (size_t)kc * ((size_t)Mt * 256) * N;
      #pragma unroll
      for (int f = 0; f < 8; ++f) {
        const int row = m0 + f * 16;
        #pragma unroll
        for (int g = 0; g < 4; ++g)
          *(f32x4*)(Cp + (size_t)row * N + n0 + g * 16) = acc[f][g];
      }
    } else {
      unsigned short* C = (unsigned short*)Cd;
      #pragma unroll
      for (int f = 0; f < 8; ++f) {
        const int row = m0 + f * 16;
        #pragma unroll
        for (int g = 0; g < 4; ++g) {
          const int col = n0 + g * 16;
          float4 bv = *(const float4*)(biasd + col);
          uint2 o;
          o.x = f2bf(acc[f][g][0] + bv.x) | ((uint32_t)f2bf(acc[f][g][1] + bv.y) << 16);
          o.y = f2bf(acc[f][g][2] + bv.z) | ((uint32_t)f2bf(acc[f][g][3] + bv.w) << 16);
          *(uint2*)(C + (size_t)row * N + col) = o;
        }
      }
    }
    #pragma unroll
    for (int f = 0; f < 8; ++f)
      #pragma unroll
      for (int g = 0; g < 4; ++g)
        acc[f][g] = (f32x4){0.f, 0.f, 0.f, 0.f};
  };

  auto tile_body = [&](int tau, const char* buf, char* obuf) {
    if (tau + 1 < TT) stage_tile(tau + 1, obuf);
    load_af(0, buf); load_bf(0, buf);
    mfma_quad(0, 0);
    __builtin_amdgcn_sched_barrier(0);
    load_bf(1, buf);
    mfma_quad(0, 1);
    __builtin_amdgcn_sched_barrier(0);
    load_af(1, buf);
    mfma_quad(1, 1);
    __builtin_amdgcn_sched_barrier(0);
    load_bf(0, buf);
    mfma_quad(1, 0);
    __builtin_amdgcn_sched_barrier(0);
    if (tau + 1 < TT)
      asm volatile("s_waitcnt vmcnt(0)" ::: "memory");
    __builtin_amdgcn_s_barrier();
    if ((tau + 1) % NK == 0) epilogue(tau / NK);
  };

  stage_tile(0, lds0);
  asm volatile("s_waitcnt vmcnt(0)" ::: "memory");
  __builtin_amdgcn_sched_barrier(0);
  __builtin_amdgcn_s_barrier();

  for (int it = 0; it < TT / 2; ++it) {
    tile_body(2 * it,     lds0, lds1);
    tile_body(2 * it + 1, lds1, lds0);
  }
}

// ---------- 256x256 8-wave GEMM, BK=32 TRIPLE-buffer, prefetch depth 2 ----------
// PARTIAL now writes bf16-packed partials (halves split-K HBM traffic).
template <int NK, int NN, bool PARTIAL>
__global__ __launch_bounds__(512, 1) void gemm_tb(
    const unsigned short* __restrict__ A,
    const unsigned short* __restrict__ Bt,
    const float* __restrict__ bias,
    void* __restrict__ Cout,
    int Mt, int NtG, int KC, int Kfull) {
  constexpr int TT = NK * NN;
  static_assert(TT >= 4, "need >=4 tiles");
  __shared__ unsigned short lds[3 * 2 * 256 * 32];   // 98304 B

  const int nwg = Mt * NtG * KC;
  const int cpx = nwg >> 3;
  const int bid = blockIdx.x;
  const int nb = (bid & 7) * cpx + (bid >> 3);       // bijective XCD swizzle
  const int kc = nb / (Mt * NtG);
  const int r2 = nb % (Mt * NtG);
  const int bm = r2 / NtG;
  const int ng = r2 % NtG;
  const int N = NtG * NN * 256;
  const size_t koff = (size_t)kc * (NK * 32);

  const int tid = threadIdx.x;
  const int wv = tid >> 6, ln = tid & 63;
  const int wm = wv >> 2, wn = wv & 3;     // 2 M-waves x 4 N-waves

  f32x4 acc[8][4] = {};
  bf16x8 af[8];
  bf16x8 bfb[4];

  auto stage_tile = [&](int tt, char* dst) {
    const int kt = tt % NK;
    const int bnn = ng * NN + tt / NK;
    #pragma unroll
    for (int j = 0; j < 2; ++j) {
      const int lr = j * 128 + wv * 16 + (ln >> 2);
      const int srcslot = (ln & 3) ^ ((lr >> 1) & 3);
      async_copy16(dst + (j * 128 + wv * 16) * 64 + ln * 16,
                   A + (size_t)(bm * 256 + lr) * Kfull + koff + kt * 32 + srcslot * 8);
      async_copy16(dst + 16384 + (j * 128 + wv * 16) * 64 + ln * 16,
                   Bt + (size_t)(bnn * 256 + lr) * Kfull + koff + kt * 32 + srcslot * 8);
    }
  };
  auto load_frags = [&](const char* buf) {
    const int kq = ln >> 4;
    #pragma unroll
    for (int f = 0; f < 8; ++f) {
      const int lr = wm * 128 + f * 16 + (ln & 15);
      af[f] = *(const bf16x8*)(buf + lr * 64 + ((kq ^ ((lr >> 1) & 3)) * 16));
    }
    #pragma unroll
    for (int g = 0; g < 4; ++g) {
      const int lr = wn * 64 + g * 16 + (ln & 15);
      bfb[g] = *(const bf16x8*)(buf + 16384 + lr * 64 + ((kq ^ ((lr >> 1) & 3)) * 16));
    }
  };
  auto epilogue = [&](int nt) {
    const int m0 = bm * 256 + wm * 128 + (ln & 15);
    const int n0 = (ng * NN + nt) * 256 + wn * 64 + ((ln >> 4) << 2);
    if (PARTIAL) {
      // bf16 partials: halves split-K write traffic (precision analyzed OK)
      unsigned short* Cp = (unsigned short*)Cout + (size_t)kc * ((size_t)Mt * 256) * N;
      #pragma unroll
      for (int f = 0; f < 8; ++f) {
        const int row = m0 + f * 16;
        #pragma unroll
        for (int g = 0; g < 4; ++g) {
          const int col = n0 + g * 16;
          uint2 o;
          o.x = f2bf(acc[f][g][0]) | ((uint32_t)f2bf(acc[f][g][1]) << 16);
          o.y = f2bf(acc[f][g][2]) | ((uint32_t)f2bf(acc[f][g][3]) << 16);
          *(uint2*)(Cp + (size_t)row * N + col) = o;
        }
      }
    } else {
      unsigned short* C = (unsigned short*)Cout;
      #pragma unroll
      for (int f = 0; f < 8; ++f) {
        const int row = m0 + f * 16;
        #pragma unroll
        for (int g = 0; g < 4; ++g) {
          const int col = n0 + g * 16;
          float4 bv = *(const float4*)(bias + col);
          uint2 o;
          o.x = f2bf(acc[f][g][0] + bv.x) | ((uint32_t)f2bf(acc[f][g][1] + bv.y) << 16);
          o.y = f2bf(acc[f][g][2] + bv.z) | ((uint32_t)f2bf(acc[f][g][3] + bv.w) << 16);
          *(uint2*)(C + (size_t)row * N + col) = o;
        }
      }
    }
    #pragma unroll
    for (int f = 0; f < 8; ++f)
      #pragma unroll
      for (int g = 0; g < 4; ++g)
        acc[f][g] = (f32x4){0.f, 0.f, 0.f, 0.f};
  };

  char* b0 = (char*)lds;
  char* b1 = (char*)lds + 32768;
  char* b2 = (char*)lds + 65536;

  stage_tile(0, b0);
  stage_tile(1, b1);
  asm volatile("s_waitcnt vmcnt(4)" ::: "memory");
  __builtin_amdgcn_sched_barrier(0);
  __builtin_amdgcn_s_barrier();

  for (int t = 0; t < TT; ++t) {
    if (t + 2 < TT) stage_tile(t + 2, b2);
    load_frags(b0);
    __builtin_amdgcn_s_setprio(1);
    #pragma unroll
    for (int f = 0; f < 8; ++f)
      #pragma unroll
      for (int g = 0; g < 4; ++g)
        acc[f][g] = __builtin_amdgcn_mfma_f32_16x16x32_bf16(
            bfb[g], af[f], acc[f][g], 0, 0, 0);
    __builtin_amdgcn_s_setprio(0);
    __builtin_amdgcn_sched_barrier(0);
    if (t + 2 < TT) {
      asm volatile("s_waitcnt vmcnt(4)" ::: "memory");
    } else if (t + 1 < TT) {
      asm volatile("s_waitcnt vmcnt(0)" ::: "memory");
    }
    __builtin_amdgcn_s_barrier();
    if ((t + 1) % NK == 0) epilogue(t / NK);
    char* tmp = b0; b0 = b1; b1 = b2; b2 = tmp;
  }
}

// ---------- reduce 4 bf16 partials + bias -> f32 out ----------
__global__ void reduce4_bias(const unsigned short* __restrict__ p,
                             const float* __restrict__ bo,
                             float* __restrict__ out) {
  const size_t S = (size_t)8192 * 512;
  size_t i = ((size_t)blockIdx.x * 256 + threadIdx.x) * 4;
  uint2 a = *(const uint2*)(p + i);
  uint2 b = *(const uint2*)(p + S + i);
  uint2 c = *(const uint2*)(p + 2 * S + i);
  uint2 d = *(const uint2*)(p + 3 * S + i);
  float4 bb = *(const float4*)(bo + (int)(i & 511));
  float4 o;
  o.x = bflo(a.x) + bflo(b.x) + bflo(c.x) + bflo(d.x) + bb.x;
  o.y = bfhi(a.x) + bfhi(b.x) + bfhi(c.x) + bfhi(d.x) + bb.y;
  o.z = bflo(a.y) + bflo(b.y) + bflo(c.y) + bflo(d.y) + bb.z;
  o.w = bfhi(a.y) + bfhi(b.y) + bfhi(c.y) + bfhi(d.y) + bb.w;
  *(float4*)(out + i) = o;
}

// ---------- MFMA energy + mask + softmax -> P (f32, 8192 x 64) ----------
__global__ __launch_bounds__(256) void energy_mfma(
    const unsigned short* __restrict__ Q,
    const unsigned short* __restrict__ Kb,
    const int* __restrict__ mask,
    float* __restrict__ P) {
  const int wave = threadIdx.x >> 6, ln = threadIdx.x & 63;
  const int t2 = (blockIdx.x * 4 + wave) * 2;
  const int r16 = ln & 15;
  const int g = ln >> 4;
  const size_t rowoff = (size_t)(t2 + (r16 >> 3)) * 4096 + (r16 & 7) * 512 + g * 8;
  const unsigned short* qb = Q + rowoff;
  const unsigned short* kb = Kb + rowoff;

  f32x4 acc = {};
  #pragma unroll
  for (int s = 0; s < 16; ++s) {
    bf16x8 qf = *(const bf16x8*)(qb + s * 32);
    bf16x8 kf = *(const bf16x8*)(kb + s * 32);
    acc = __builtin_amdgcn_mfma_f32_16x16x32_bf16(qf, kf, acc, 0, 0, 0);
  }

  const int ct = r16 >> 3, j = r16 & 7;
  const bool valid = ((g >> 1) == ct);
  const int tok = t2 + ct;
  float pv[4];
  #pragma unroll
  for (int r = 0; r < 4; ++r) {
    const int i = (g & 1) * 4 + r;
    float e = acc[r] * 0.044194173824159216f;          // 1/sqrt(512)
    int mk = 1;
    if (valid) mk = mask[(size_t)tok * 64 + i * 8 + j];
    if (mk == 0) e = -1e30f;
    float m = e;
    m = fmaxf(m, __shfl_xor(m, 1, 64));
    m = fmaxf(m, __shfl_xor(m, 2, 64));
    m = fmaxf(m, __shfl_xor(m, 4, 64));
    float p = __expf(e - m);
    float sum = p;
    sum += __shfl_xor(sum, 1, 64);
    sum += __shfl_xor(sum, 2, 64);
    sum += __shfl_xor(sum, 4, 64);
    pv[r] = p / sum;
  }
  if (valid) {
    #pragma unroll
    for (int r = 0; r < 4; ++r) {
      const int i = (g & 1) * 4 + r;
      P[(size_t)tok * 64 + i * 8 + j] = pv[r];
    }
  }
}

// ---------- PV: out2 rows in the (B,H,L,E)->(B,L,H*E) reshaped layout ----------
__global__ __launch_bounds__(256) void pv_kernel(
    const float* __restrict__ P,
    const unsigned short* __restrict__ Vb,
    unsigned short* __restrict__ out2) {
  const int wave = threadIdx.x >> 6, lane = threadIdx.x & 63;
  const int t = blockIdx.x * 4 + wave;
  const unsigned short* Vr = Vb + (size_t)t * 4096;
  float att = P[(size_t)t * 64 + lane];

  uint4 v4[8];
  #pragma unroll
  for (int jj = 0; jj < 8; ++jj)
    v4[jj] = *(const uint4*)(Vr + jj * 512 + lane * 8);

  const int nb = t >> 11, l = t & 2047;
  const size_t tok_base = (size_t)nb * 8388608 + (size_t)(l >> 3) * 4096 +
                          (size_t)(l & 7) * 512 + lane * 8;
  #pragma unroll
  for (int hh = 0; hh < 8; ++hh) {
    float accv[8] = {0.f, 0.f, 0.f, 0.f, 0.f, 0.f, 0.f, 0.f};
    #pragma unroll
    for (int jj = 0; jj < 8; ++jj) {
      float a = __shfl(att, hh * 8 + jj, 64);
      accv[0] += a * bflo(v4[jj].x); accv[1] += a * bfhi(v4[jj].x);
      accv[2] += a * bflo(v4[jj].y); accv[3] += a * bfhi(v4[jj].y);
      accv[4] += a * bflo(v4[jj].z); accv[5] += a * bfhi(v4[jj].z);
      accv[6] += a * bflo(v4[jj].w); accv[7] += a * bfhi(v4[jj].w);
    }
    uint4 o;
    o.x = f2bf(accv[0]) | ((uint32_t)f2bf(accv[1]) << 16);
    o.y = f2bf(accv[2]) | ((uint32_t)f2bf(accv[3]) << 16);
    o.z = f2bf(accv[4]) | ((uint32_t)f2bf(accv[5]) << 16);
    o.w = f2bf(accv[6]) | ((uint32_t)f2bf(accv[7]) << 16);
    *(uint4*)(out2 + tok_base + (size_t)hh * 1048576) = o;
  }
}

// ---------- launch ----------
extern "C" void kernel_launch(void* const* d_in, const int* in_sizes, int n_in,
                              void* d_out, int out_size, void* d_ws, size_t ws_size,
                              hipStream_t stream) {
  const float* values  = (const float*)d_in[0];
  const float* keys    = (const float*)d_in[1];
  const float* queries = (const float*)d_in[2];
  const int*   mask    = (const int*)d_in[3];
  const float* Wv = (const float*)d_in[4];
  const float* bv = (const float*)d_in[5];
  const float* Wk = (const float*)d_in[6];
  const float* bk = (const float*)d_in[7];
  const float* Wq = (const float*)d_in[8];
  const float* bq = (const float*)d_in[9];
  const float* Wo = (const float*)d_in[10];
  const float* bo = (const float*)d_in[11];

  unsigned short* xv  = (unsigned short*)d_ws;            // 8192*512 x3 (v,k,q)
  unsigned short* xk  = xv + 8192 * 512;
  unsigned short* xq  = xk + 8192 * 512;
  unsigned short* Wvt = xq + 8192 * 512;                  // 4096*512 x3 (v,k,q)
  unsigned short* Wkt = Wvt + 4096 * 512;
  unsigned short* Wqt = Wkt + 4096 * 512;
  unsigned short* Wot = Wqt + 4096 * 512;                 // 512*4096 (N x K)
  float*          P   = (float*)(Wot + 4096 * 512);       // 8192*64 f32
  unsigned short* bufA = (unsigned short*)(P + 8192 * 64); // 8192*4096 bf16
  unsigned short* bufB = bufA + (size_t)8192 * 4096;       // 8192*4096 bf16

  const int nx = 8192 * 512;
  cvt3_f32_bf16<<<dim3(nx / 8 / 256, 3), 256, 0, stream>>>(
      values, keys, queries, (uint32_t*)xv, nx);

  transpose3_to_bf16<<<dim3(4096 / 32, 512 / 32, 3), dim3(32, 8), 0, stream>>>(
      Wv, Wk, Wq, Wvt, 512, 4096);
  transpose_to_bf16<<<dim3(512 / 32, 4096 / 32), dim3(32, 8), 0, stream>>>(
      Wo, Wot, 4096, 512);

  // fused Q+K projections: NN=4, NtG=8 (4 n-groups per matrix), 256 blocks
  gemm256<8, 4, false, true><<<256, 512, 0, stream>>>(
      xq, Wqt, bq, bufA, xk, Wkt, bk, bufB, 32, 8, 1, 512);

  // energy + softmax -> P  (Q, K dead afterwards)
  energy_mfma<<<8192 / 8, 256, 0, stream>>>(bufA, bufB, mask, P);

  // V -> bufA (BK=32 triple-buffer counted-vmcnt)
  gemm_tb<16, 2, false><<<256, 512, 0, stream>>>(
      xv, Wvt, bv, bufA, 32, 8, 1, 512);

  // PV -> bufB (overwrites K)
  pv_kernel<<<8192 / 4, 256, 0, stream>>>(P, bufA, bufB);

  // final: split-K=4 bf16 partials via gemm_tb, then reduce+bias (f32 out)
  gemm_tb<32, 1, true><<<256, 512, 0, stream>>>(
      bufB, Wot, nullptr, bufA, 32, 2, 4, 4096);
  reduce4_bias<<<4096, 256, 0, stream>>>(bufA, bo, (float*)d_out);
}